// Round 8
// baseline (196.899 us; speedup 1.0000x reference)
//
#include <hip/hip_runtime.h>
#include <stdint.h>

// EnergyWell, round 8: R5/R7 structure, TWO tiles per wave, all loads
// front-issued — the final MLP discriminator.
//
// R7 post-mortem: 1.33x occupancy -> +7%; effective read pinned ~2.8 TB/s.
// Surviving theories: (a) XCD fabric read path ~1.1-1.3 lines/cyc/XCD,
// (b) per-CU outstanding-line-fill cap x ~375ns latency = 2.8 TB/s. Only
// software-addressable variant: wave-level MLP. This round: each wave owns
// tiles 2w and 2w+1, issues boxes -> tileA(7 loads) -> tileB(7 loads) before
// any compute, so tile A computes at vmcnt(7) with B's loads in flight.
// launch_bounds(256,6): 24 waves/CU x 8.5KB = 204 KB/CU in flight (1.5x R7).
// If time stays ~49-54us => HW cap => declare roofline next round.

#define C_WELLS 64

template <int CTRL>
__device__ __forceinline__ unsigned long long dpp64(unsigned long long k) {
    int lo = (int)(unsigned)k;
    int hi = (int)(unsigned)(k >> 32);
    lo = __builtin_amdgcn_update_dpp(0, lo, CTRL, 0xF, 0xF, true);
    hi = __builtin_amdgcn_update_dpp(0, hi, CTRL, 0xF, 0xF, true);
    return ((unsigned long long)(unsigned)hi << 32) | (unsigned)lo;
}

__device__ __forceinline__ unsigned long long umin64(unsigned long long a,
                                                     unsigned long long b) {
    return a < b ? a : b;   // v_cmp_lt_u64 + 2 cndmask
}

__global__ __launch_bounds__(256, 6)
void energy_well_kernel(const float2* __restrict__ inst_pos,   // N
                        const float2* __restrict__ half_sizes, // N
                        const float*  __restrict__ well_boxes, // 64*4 {xl,yl,xh,yh}
                        const int4*   __restrict__ avail4,     // N*16
                        const float*  __restrict__ exponents,  // N
                        float* __restrict__ out,               // N
                        int N, int nT16, int nW)
{
    const int lane = threadIdx.x & 63;
    const int sub  = lane & 3;                 // quad member: wells [16sub,16sub+16)
    const int wave = (int)((blockIdx.x * blockDim.x + threadIdx.x) >> 6);
    if (wave >= nW) return;

    const int tileA = 2 * wave;
    const int tileB = 2 * wave + 1;            // may be == nT16 (tail): clamped loads
    const int q     = lane >> 2;               // instance-in-tile 0..15

    // ---- box loads first (needed by both tiles) ----
    // this lane's two y-rows (iy = 2*sub, 2*sub+1): 4 per-lane VMEM
    const float ylA_ = well_boxes[64 * sub + 1];
    const float yhA_ = well_boxes[64 * sub + 3];
    const float ylB_ = well_boxes[64 * sub + 33];
    const float yhB_ = well_boxes[64 * sub + 35];
    // x-edges: wave-uniform, compile-time offsets -> s_load (SGPRs)
    float xlv[8], xhv[8];
    #pragma unroll
    for (int ix = 0; ix < 8; ++ix) {
        xlv[ix] = well_boxes[4 * ix + 0];
        xhv[ix] = well_boxes[4 * ix + 2];
    }

    // ---- tile A loads (7 VMEM) ----
    const int iA  = tileA * 16 + q;
    const int iiA = iA < N ? iA : N - 1;
    const int4* aA = avail4 + ((size_t)iiA * 16 + (size_t)sub * 4);
    const int4 aA0 = aA[0], aA1 = aA[1], aA2 = aA[2], aA3 = aA[3];
    const float2 pA = inst_pos[iiA];
    const float2 hA = half_sizes[iiA];
    const float  eA = exponents[iiA];

    // ---- tile B loads (7 VMEM, stay in flight during A's compute) ----
    const int iB  = tileB * 16 + q;
    const int iiB = iB < N ? iB : N - 1;
    const int4* aB = avail4 + ((size_t)iiB * 16 + (size_t)sub * 4);
    const int4 aB0 = aB[0], aB1 = aB[1], aB2 = aB[2], aB3 = aB[3];
    const float2 pB = inst_pos[iiB];
    const float2 hB = half_sizes[iiB];
    const float  eB = exponents[iiB];

    // ---- compute one tile (fully inlined lambda; R7's lean path) ----
    auto process = [&](int i, const int4& v0, const int4& v1,
                       const int4& v2, const int4& v3,
                       const float2& p, const float2& h, float e) {
        const float xm = p.x - h.x, xp_ = p.x + h.x;
        const float ym = p.y - h.y, yp_ = p.y + h.y;

        float dxv[8];
        #pragma unroll
        for (int ix = 0; ix < 8; ++ix)
            dxv[ix] = fmaxf(fmaxf(xlv[ix] - xm, xp_ - xhv[ix]), 0.0f); // v_max3
        const float dyA = fmaxf(fmaxf(ylA_ - ym, yp_ - yhA_), 0.0f);
        const float dyB = fmaxf(fmaxf(ylB_ - ym, yp_ - yhB_), 0.0f);

        // keyed scan: 2 independent chains of 8, then merge
        const unsigned gbase = (unsigned)(sub << 4);
        unsigned long long acc0 = ~0ull, acc1 = ~0ull;
        #pragma unroll
        for (int j = 0; j < 4; ++j) {
            const int4 a4 = (j == 0) ? v0 : (j == 1) ? v1 : (j == 2) ? v2 : v3;
            #pragma unroll
            for (int k = 0; k < 4; ++k) {
                const int c2 = 4 * j + k;                   // local well 0..15
                const int avw = (k == 0) ? a4.x : (k == 1) ? a4.y
                              : (k == 2) ? a4.z : a4.w;
                const float dy   = (c2 < 8) ? dyA : dyB;
                const float dist = dxv[c2 & 7] + dy;
                unsigned long long key =
                    (((unsigned long long)__float_as_uint(dist)) << 6)
                    | (unsigned long long)(gbase + (unsigned)c2);
                key = avw ? key : ~0ull;                    // mask unavailable
                if (c2 & 1) acc1 = umin64(acc1, key);
                else        acc0 = umin64(acc0, key);
            }
        }
        unsigned long long kmin = umin64(acc0, acc1);

        // cross-sub (quad) reduce, VALU pipe via DPP
        kmin = umin64(kmin, dpp64<0xB1>(kmin));   // quad_perm xor 1
        kmin = umin64(kmin, dpp64<0x4E>(kmin));   // quad_perm xor 2

        // decode winner
        const int g = (int)(kmin & 63);
        const int s = g & 7;
        float a0 = (s & 1) ? dxv[1] : dxv[0];
        float a1 = (s & 1) ? dxv[3] : dxv[2];
        float a2 = (s & 1) ? dxv[5] : dxv[4];
        float a3 = (s & 1) ? dxv[7] : dxv[6];
        float b0 = (s & 2) ? a1 : a0;
        float b1 = (s & 2) ? a3 : a2;
        const float dxs = (s & 4) ? b1 : b0;
        const float dys = (g & 8) ? dyB : dyA;

        if (((g >> 4) == sub) && (i < N)) {       // unique winner lane/quad
            float energy;
            if (e == 2.0f) energy = dxs * dxs + dys * dys;
            else           energy = powf(dxs, e) + powf(dys, e);
            out[i] = energy;
        }
    };

    process(iA, aA0, aA1, aA2, aA3, pA, hA, eA);   // waits vmcnt(7): B in flight
    process(iB, aB0, aB1, aB2, aB3, pB, hB, eB);   // iB<N guards tail tile

}

extern "C" void kernel_launch(void* const* d_in, const int* in_sizes, int n_in,
                              void* d_out, int out_size, void* d_ws, size_t ws_size,
                              hipStream_t stream)
{
    // 0: inst_pos (N*2 f32), 1: half_inst_sizes (N*2 f32), 2: inst_areas (UNUSED),
    // 3: well_boxes (64*4 f32), 4: inst_cr_avail_map (N*64 int), 5: exponents (N)
    const float2* inst_pos   = (const float2*)d_in[0];
    const float2* half_sizes = (const float2*)d_in[1];
    const float*  well_boxes = (const float*)d_in[3];
    const int4*   avail4     = (const int4*)d_in[4];
    const float*  exponents  = (const float*)d_in[5];
    float* out = (float*)d_out;

    const int N = in_sizes[5];
    const int nT16 = (N + 15) / 16;        // 16-instance tiles (31250)
    const int nW   = (nT16 + 1) / 2;       // two tiles per wave (15625)
    const int blocks = (nW + 3) / 4;       // 4 waves/block

    energy_well_kernel<<<dim3(blocks), dim3(256), 0, stream>>>(
        inst_pos, half_sizes, well_boxes, avail4, exponents, out, N, nT16, nW);
}